// Round 17
// baseline (218.137 us; speedup 1.0000x reference)
//
#include <hip/hip_runtime.h>
#include <math.h>

#define B_   4
#define NQ_  300
#define DIM_ 256
#define H_   8
#define HD_  32
#define N_   4096

typedef _Float16 f16;
typedef f16   f16x8 __attribute__((ext_vector_type(8)));
typedef f16   f16x4 __attribute__((ext_vector_type(4)));
typedef float f32x4 __attribute__((ext_vector_type(4)));

// ---------------------------------------------------------------------------
// Weight prep: WT[z][n][k] = W_z[k][n] * (z==0 ? qscale : 1), f16.
// ---------------------------------------------------------------------------
__global__ __launch_bounds__(256) void prep_wt(
    const float* __restrict__ Wq, const float* __restrict__ Wk,
    const float* __restrict__ Wv, const float* __restrict__ Wp,
    f16* __restrict__ WT, float qscale)
{
  __shared__ float t[64][65];
  const int z = blockIdx.z;
  const float* W = z == 0 ? Wq : z == 1 ? Wk : z == 2 ? Wv : Wp;
  const float s = z == 0 ? qscale : 1.0f;
  f16* O = WT + (size_t)z * 65536;
  const int k0 = blockIdx.y * 64, n0 = blockIdx.x * 64;
  const int r = threadIdx.x >> 2, c0 = (threadIdx.x & 3) * 16;
#pragma unroll
  for (int c = 0; c < 16; c += 4) {
    float4 v = *(const float4*)(W + (size_t)(k0 + r) * 256 + n0 + c0 + c);
    t[r][c0 + c] = v.x; t[r][c0 + c + 1] = v.y;
    t[r][c0 + c + 2] = v.z; t[r][c0 + c + 3] = v.w;
  }
  __syncthreads();
  f16* orow = O + (size_t)(n0 + r) * 256 + k0 + c0;
#pragma unroll
  for (int c = 0; c < 16; c += 4) {
    f16x4 p;
    p[0] = (f16)(t[c0 + c + 0][r] * s);
    p[1] = (f16)(t[c0 + c + 1][r] * s);
    p[2] = (f16)(t[c0 + c + 2][r] * s);
    p[3] = (f16)(t[c0 + c + 3][r] * s);
    *(f16x4*)(orow + c) = p;
  }
}

// ---------------------------------------------------------------------------
// MFMA GEMM body: C = A @ (WT^T) + bias*scale.  WT is [n][k] f16.
// nbt = number of 64-col B tiles per block (bn-fusion: A staged once, reused).
// mode 0: fp32 row-major out; 1: f16 row-major;
// mode 3: f16 head-major  [b][h=n>>5][nrow=m&4095][d=n&31]  (K and V).
// a_f16 == 2: A is head-major X  [b][h=k>>5][q][d=k&31]  (gemm_out path).
// ---------------------------------------------------------------------------
__device__ __forceinline__ void gemm_body(
    const void* __restrict__ Ain, const f16* __restrict__ WT,
    const float* __restrict__ bias, void* __restrict__ C,
    int M, float scale, int a_f16, int mode, int bm, int bn, int nbt, int tid)
{
  __shared__ f16 As[64][40];
  __shared__ f16 Bs[4][64][40];
  const int lane = tid & 63;
  const int wv = tid >> 6;
  const int l15 = lane & 15, g = lane >> 4;
  const int arow = tid >> 2, akq = (tid & 3) * 8;

  f32x4 acc[4][4];
#pragma unroll
  for (int t = 0; t < 4; ++t)
#pragma unroll
    for (int nt = 0; nt < 4; ++nt) acc[t][nt] = (f32x4){0.f, 0.f, 0.f, 0.f};

  for (int k0 = 0; k0 < 256; k0 += 32) {
    {
      const int gm = bm + arow;
      f16x8 av;
      if (gm < M) {
        if (a_f16 == 2) {
          // head-major X: [b][h][q][32]
          const int bb2 = gm / NQ_, qq2 = gm % NQ_;
          const int kk = k0 + akq;
          av = *(const f16x8*)((const f16*)Ain +
              (((size_t)(bb2 * H_ + (kk >> 5)) * NQ_) + qq2) * 32 + (kk & 31));
        } else if (a_f16 == 1) {
          av = *(const f16x8*)((const f16*)Ain + (size_t)gm * 256 + k0 + akq);
        } else {
          const float* ap = (const float*)Ain + (size_t)gm * 256 + k0 + akq;
          float4 a0 = *(const float4*)ap;
          float4 a1 = *(const float4*)(ap + 4);
          av[0] = (f16)a0.x; av[1] = (f16)a0.y; av[2] = (f16)a0.z; av[3] = (f16)a0.w;
          av[4] = (f16)a1.x; av[5] = (f16)a1.y; av[6] = (f16)a1.z; av[7] = (f16)a1.w;
        }
      } else {
#pragma unroll
        for (int i = 0; i < 8; ++i) av[i] = (f16)0.f;
      }
      *(f16x8*)&As[arow][akq] = av;
      for (int t = 0; t < nbt; ++t)
        *(f16x8*)&Bs[t][arow][akq] =
            *(const f16x8*)(WT + (size_t)(bn + t * 64 + arow) * 256 + k0 + akq);
    }
    __syncthreads();
    const f16x8 af = *(const f16x8*)&As[wv * 16 + l15][g * 8];
    for (int t = 0; t < nbt; ++t) {
#pragma unroll
      for (int nt = 0; nt < 4; ++nt) {
        const f16x8 bf = *(const f16x8*)&Bs[t][nt * 16 + l15][g * 8];
        acc[t][nt] = __builtin_amdgcn_mfma_f32_16x16x32_f16(af, bf, acc[t][nt], 0, 0, 0);
      }
    }
    __syncthreads();
  }

  for (int t = 0; t < nbt; ++t) {
#pragma unroll
    for (int nt = 0; nt < 4; ++nt) {
      const int n = bn + t * 64 + nt * 16 + l15;
      const float bv = bias[n] * scale;
#pragma unroll
      for (int r = 0; r < 4; ++r) {
        const int m = bm + wv * 16 + g * 4 + r;
        if (m >= M) continue;
        const float v = acc[t][nt][r] + bv;
        if (mode == 0)      ((float*)C)[(size_t)m * 256 + n] = v;
        else if (mode == 1) ((f16*)C)[(size_t)m * 256 + n] = (f16)v;
        else                ((f16*)C)[((((size_t)(m >> 12)) * H_ + (n >> 5)) * N_
                                       + (m & 4095)) * 32 + (n & 31)] = (f16)v;
      }
    }
  }
}

// One block = 64 rows x full 256 cols (nbt=4: A staged once, 4x fewer A reads).
// Grid 768 = 8 XCDs x 96, chunked.  z=0: Q, z=1: K (head-major), z=2: V
// (head-major [b][h][n][32] -- attn stages V through LDS).
__global__ __launch_bounds__(256) void proj_qkv(
    const float* __restrict__ query, const float* __restrict__ kin,
    const float* __restrict__ vin, const f16* __restrict__ WT,
    const float* __restrict__ bq, const float* __restrict__ bk,
    const float* __restrict__ bv, f16* __restrict__ Qf,
    f16* __restrict__ Kf, f16* __restrict__ Vtf, float qscale)
{
  const int bid = blockIdx.x;
  const int lg  = (bid & 7) * 96 + (bid >> 3);   // 768 = 8 * 96, bijective
  const int z   = lg >> 8;                        // lg / 256
  const int bm  = (lg & 255) * 64;
  if (z == 0) {
    if (bm >= B_ * NQ_) return;
    gemm_body(query, WT, bq, Qf, B_ * NQ_, qscale, 0, 1, bm, 0, 4, threadIdx.x);
  } else if (z == 1) {
    gemm_body(kin, WT + 65536, bk, Kf, B_ * N_, 1.0f, 0, 3, bm, 0, 4, threadIdx.x);
  } else {
    gemm_body(vin, WT + 2 * 65536, bv, Vtf, B_ * N_, 1.0f, 0, 3, bm, 0, 4, threadIdx.x);
  }
}

__global__ __launch_bounds__(256) void gemm_out(
    const f16* __restrict__ X, const f16* __restrict__ WT,
    const float* __restrict__ bp, float* __restrict__ out)
{
  gemm_body(X, WT + 3 * 65536, bp, out, B_ * NQ_, 1.0f, 2, 0,
            blockIdx.y * 64, blockIdx.x * 64, 1, threadIdx.x);
}

// ---------------------------------------------------------------------------
// RPE MLP, fp32 (rpe ~±1500; must not round). lane = position j, wave owns a
// 128-wide r-slice; all weight reads wave-uniform -> scalar loads, no LDS.
// Output layout head-major: out[q][h*64 + j] so attn reads dense 256B runs.
// ---------------------------------------------------------------------------
__global__ __launch_bounds__(256) void rpe_kernel(
    const float* __restrict__ refpts,
    const float* __restrict__ W1x, const float* __restrict__ b1x, const float* __restrict__ W2x,
    const float* __restrict__ W1y, const float* __restrict__ b1y, const float* __restrict__ W2y,
    float* __restrict__ rpx, float* __restrict__ rpy)
{
  __shared__ float sRed[4][64][9];   // pad 9: head-major read is stride-9, conflict-free
  const int tid = threadIdx.x;
  const int lane = tid & 63;
  const int wv = __builtin_amdgcn_readfirstlane(tid >> 6);
  const int bq = blockIdx.x;
  const int axis = blockIdx.y;
  const float* W1 = axis ? W1y : W1x;
  const float* b1 = axis ? b1y : b1x;
  const float* W2 = axis ? W2y : W2x;
  float* out = axis ? rpy : rpx;

  const float c  = refpts[bq * 4 + axis];
  const float sz = refpts[bq * 4 + 2 + axis];
  const float pos = (lane + 0.5f) * 16.0f;
  const float d0 = c - 0.5f * sz - pos;
  const float d1 = c + 0.5f * sz - pos;
  float acc[8] = {};
  const int r0 = wv * 128;
#pragma unroll 4
  for (int i = 0; i < 128; ++i) {
    const int r = r0 + i;
    const float w10 = W1[r], w11 = W1[512 + r], bb = b1[r];
    const float hv = fmaxf(fmaf(d0, w10, fmaf(d1, w11, bb)), 0.0f);
    const float* w2r = W2 + r * 8;
#pragma unroll
    for (int hh = 0; hh < 8; ++hh) acc[hh] += hv * w2r[hh];
  }
#pragma unroll
  for (int hh = 0; hh < 8; ++hh) sRed[wv][lane][hh] = acc[hh];
  __syncthreads();
  for (int idx = tid; idx < 512; idx += 256) {
    const int hh = idx >> 6, jj = idx & 63;       // out[q][hh*64 + jj]
    out[(size_t)bq * 512 + idx] =
        sRed[0][jj][hh] + sRed[1][jj][hh] + sRed[2][jj][hh] + sRed[3][jj][hh];
  }
}

// ---------------------------------------------------------------------------
// MFMA attention.  R13 confirmed request-queue model: V coalescing took attn
// 61 -> ~35us (off top-5), total -25us.  Remaining attn cost: per-sub-pass
// serial load-wait (sp+1 loads issued only after sp completes; ~200-900cy
// exposed per sp).  No barriers in the sp loop (wave-private LDS tile), so
// counted-vmcnt pipelining works at source level: 2-deep register double-
// buffer (A/B sets, fully static schedule) gives each sp's loads a whole
// computeSP (~500+cy) of cover.  +32 VGPR (~110 total, under the (512,4)
// 128 cap); vtile stays single-buffered (in-wave lgkmcnt orders the WAR).
// ---------------------------------------------------------------------------
__global__ __launch_bounds__(512, 4) void attn_mfma(
    const f16* __restrict__ Qf, const f16* __restrict__ Kf,
    const f16* __restrict__ Vtf, const float* __restrict__ rpx,
    const float* __restrict__ rpy, const int* __restrict__ mask,
    f16* __restrict__ X)
{
  __shared__ float smask[N_];          // -100*log2e*mask
  __shared__ float srx[16][68];        // rpe_x * log2e
  __shared__ float sry[16][68];        // rpe_y * log2e
  __shared__ union {
    f16 vtile[8][64 * 36];             // per-wave V tile, 72B row stride
    struct {
      float mO[7][8][64];
      float mlm[7][16];
      float mll[7][16];
    } m;
  } ovl;

  const int tid = threadIdx.x;
  const int lane = tid & 63;
  const int kh = tid >> 6;
  // XCD-aware swizzle: grid is 640 = 8 XCDs * 80; HW assigns XCD = bid % 8.
  const int bid = blockIdx.x;
  const int lg  = (bid & 7) * 80 + (bid >> 3);
  const int qg = lg % 20;
  const int h  = (lg / 20) % H_;
  const int b  = lg / (20 * H_);
  const int q0 = qg * 16;
  const float L2E = 1.44269504f;

  {
    const int4* mm4 = (const int4*)(mask + b * N_);
    for (int i = tid; i < N_ / 4; i += 512) {
      int4 mm = mm4[i];
      smask[4 * i + 0] = -100.f * L2E * (float)mm.x;
      smask[4 * i + 1] = -100.f * L2E * (float)mm.y;
      smask[4 * i + 2] = -100.f * L2E * (float)mm.z;
      smask[4 * i + 3] = -100.f * L2E * (float)mm.w;
    }
  }
  for (int i = tid; i < 1024; i += 512) {
    int qq = i >> 6, j = i & 63;
    int qg2 = q0 + qq; if (qg2 > NQ_ - 1) qg2 = NQ_ - 1;
    size_t base = (size_t)(b * NQ_ + qg2) * 512 + (size_t)h * 64 + j;  // head-major
    srx[qq][j] = rpx[base] * L2E;
    sry[qq][j] = rpy[base] * L2E;
  }
  __syncthreads();

  const int l15 = lane & 15, g = lane >> 4;
  const int qrow0 = q0 + l15;
  const int qa = qrow0 > NQ_ - 1 ? NQ_ - 1 : qrow0;

  const f16x8 qf0 = *(const f16x8*)(Qf + (size_t)(b * NQ_ + qa) * 256 + h * 32 + g * 8);

  f32x4 O00 = {0.f,0.f,0.f,0.f}, O01 = {0.f,0.f,0.f,0.f};
  float lacc0 = 0.f;
  float mrun0 = -1e30f;
  const f16* kb  = Kf  + (size_t)(b * H_ + h) * N_ * 32 + g * 8;  // head-major K
  const f16* vbp = Vtf + (size_t)(b * H_ + h) * N_ * 32;          // head-major V
  f16* vt = &ovl.vtile[kh][0];

  f16x8 kfA[4], vvA[4], kfB[4], vvB[4];

#define LOADKV(KF, VV, SP) do {                                                \
    const int kbase_ = kh * 512 + (SP) * 64;                                   \
    _Pragma("unroll")                                                          \
    for (int cc = 0; cc < 4; ++cc)                                             \
      KF[cc] = *(const f16x8*)(kb + (size_t)(kbase_ + cc * 16 + l15) * 32);    \
    const f16* vsrc_ = vbp + (size_t)kbase_ * 32;                              \
    _Pragma("unroll")                                                          \
    for (int c = 0; c < 4; ++c)                                                \
      VV[c] = *(const f16x8*)(vsrc_ + c * 512 + lane * 8);                     \
  } while (0)

#define COMPUTESP(KF, VV, SP) do {                                             \
    const int kbase_ = kh * 512 + (SP) * 64;                                   \
    f32x4 s0[4];                                                               \
    float lm0 = -1e30f;                                                        \
    _Pragma("unroll")                                                          \
    for (int cc = 0; cc < 4; ++cc) {                                           \
      const int k0_ = kbase_ + cc * 16;                                        \
      f32x4 S0 = __builtin_amdgcn_mfma_f32_16x16x32_f16(                       \
          KF[cc], qf0, (f32x4){0.f,0.f,0.f,0.f}, 0, 0, 0);                     \
      const float ry0 = sry[l15][k0_ >> 6];                                    \
      const float4 rx0 = *(const float4*)&srx[l15][(k0_ & 63) + g * 4];        \
      const float4 sm = *(const float4*)&smask[k0_ + g * 4];                   \
      s0[cc][0] = fmaf(S0[0], L2E, rx0.x + sm.x + ry0);                        \
      s0[cc][1] = fmaf(S0[1], L2E, rx0.y + sm.y + ry0);                        \
      s0[cc][2] = fmaf(S0[2], L2E, rx0.z + sm.z + ry0);                        \
      s0[cc][3] = fmaf(S0[3], L2E, rx0.w + sm.w + ry0);                        \
      lm0 = fmaxf(lm0, fmaxf(fmaxf(s0[cc][0], s0[cc][1]),                      \
                             fmaxf(s0[cc][2], s0[cc][3])));                    \
    }                                                                          \
    _Pragma("unroll")                                                          \
    for (int c = 0; c < 4; ++c) {                                              \
      const int row_ = c * 16 + (lane >> 2), d0_ = (lane & 3) * 8;             \
      f16x4 lo_, hi_;                                                          \
      _Pragma("unroll")                                                        \
      for (int i = 0; i < 4; ++i) { lo_[i] = VV[c][i]; hi_[i] = VV[c][4 + i]; }\
      *(f16x4*)&vt[row_ * 36 + d0_]     = lo_;                                 \
      *(f16x4*)&vt[row_ * 36 + d0_ + 4] = hi_;                                 \
    }                                                                          \
    lm0 = fmaxf(lm0, __shfl_xor(lm0, 16));                                     \
    lm0 = fmaxf(lm0, __shfl_xor(lm0, 32));                                     \
    const float mn0 = fmaxf(mrun0, lm0);                                       \
    const float f0 = exp2f(mrun0 - mn0);                                       \
    mrun0 = mn0;                                                               \
    lacc0 *= f0;                                                               \
    _Pragma("unroll")                                                          \
    for (int r = 0; r < 4; ++r) { O00[r] *= f0; O01[r] *= f0; }                \
    _Pragma("unroll")                                                          \
    for (int cc = 0; cc < 4; ++cc) {                                           \
      f16x4 pf0;                                                               \
      _Pragma("unroll")                                                        \
      for (int r = 0; r < 4; ++r) {                                            \
        const float p0 = exp2f(s0[cc][r] - mrun0);                             \
        lacc0 += p0;                                                           \
        pf0[r] = (f16)p0;                                                      \
      }                                                                        \
      f16x4 va_, vb_;                                                          \
      _Pragma("unroll")                                                        \
      for (int i = 0; i < 4; ++i) {                                            \
        const int krow_ = cc * 16 + g * 4 + i;                                 \
        va_[i] = vt[krow_ * 36 + l15];                                         \
        vb_[i] = vt[krow_ * 36 + 16 + l15];                                    \
      }                                                                        \
      O00 = __builtin_amdgcn_mfma_f32_16x16x16f16(va_, pf0, O00, 0, 0, 0);     \
      O01 = __builtin_amdgcn_mfma_f32_16x16x16f16(vb_, pf0, O01, 0, 0, 0);     \
    }                                                                          \
  } while (0)

  // 2-deep software pipeline, fully static register-set schedule.
  LOADKV(kfA, vvA, 0);
  LOADKV(kfB, vvB, 1);
  COMPUTESP(kfA, vvA, 0);
  LOADKV(kfA, vvA, 2);
  COMPUTESP(kfB, vvB, 1);
  LOADKV(kfB, vvB, 3);
  COMPUTESP(kfA, vvA, 2);
  LOADKV(kfA, vvA, 4);
  COMPUTESP(kfB, vvB, 3);
  LOADKV(kfB, vvB, 5);
  COMPUTESP(kfA, vvA, 4);
  LOADKV(kfA, vvA, 6);
  COMPUTESP(kfB, vvB, 5);
  LOADKV(kfB, vvB, 7);
  COMPUTESP(kfA, vvA, 6);
  COMPUTESP(kfB, vvB, 7);

#undef LOADKV
#undef COMPUTESP

  lacc0 += __shfl_xor(lacc0, 16); lacc0 += __shfl_xor(lacc0, 32);

  __syncthreads();   // all waves done with vtile before mO overlays it
  if (kh > 0) {
#pragma unroll
    for (int r = 0; r < 4; ++r) {
      ovl.m.mO[kh - 1][r][lane]     = O00[r];
      ovl.m.mO[kh - 1][4 + r][lane] = O01[r];
    }
    if (lane < 16) {
      ovl.m.mlm[kh - 1][lane] = mrun0;
      ovl.m.mll[kh - 1][lane] = lacc0;
    }
  }
  __syncthreads();
  if (kh == 0) {
    float ms = mrun0;
#pragma unroll
    for (int w = 0; w < 7; ++w) ms = fmaxf(ms, ovl.m.mlm[w][l15]);
    const float fme = exp2f(mrun0 - ms);
    float lt = lacc0 * fme;
    float fw[7];
#pragma unroll
    for (int w = 0; w < 7; ++w) {
      fw[w] = exp2f(ovl.m.mlm[w][l15] - ms);
      lt += ovl.m.mll[w][l15] * fw[w];
    }
    const float rl = 1.0f / lt;
    if (qrow0 < NQ_) {
      f16* xr = X + ((size_t)(b * H_ + h) * NQ_ + qrow0) * 32;   // head-major X
      f16x4 p0, p1;
#pragma unroll
      for (int r = 0; r < 4; ++r) {
        float o0 = O00[r] * fme, o1 = O01[r] * fme;
#pragma unroll
        for (int w = 0; w < 7; ++w) {
          o0 += ovl.m.mO[w][r][lane] * fw[w];
          o1 += ovl.m.mO[w][4 + r][lane] * fw[w];
        }
        p0[r] = (f16)(o0 * rl);
        p1[r] = (f16)(o1 * rl);
      }
      *(f16x4*)(xr + g * 4) = p0;
      *(f16x4*)(xr + 16 + g * 4) = p1;
    }
  }
}

// ---------------------------------------------------------------------------
extern "C" void kernel_launch(void* const* d_in, const int* in_sizes, int n_in,
                              void* d_out, int out_size, void* d_ws, size_t ws_size,
                              hipStream_t stream)
{
  const float* query  = (const float*)d_in[0];
  const float* refpts = (const float*)d_in[1];
  const float* kin    = (const float*)d_in[2];
  const float* vin    = (const float*)d_in[3];
  const int*   mask   = (const int*)d_in[5];
  const float* Wq = (const float*)d_in[6];
  const float* bq = (const float*)d_in[7];
  const float* Wk = (const float*)d_in[8];
  const float* bk = (const float*)d_in[9];
  const float* Wv = (const float*)d_in[10];
  const float* bv = (const float*)d_in[11];
  const float* Wp = (const float*)d_in[12];
  const float* bp = (const float*)d_in[13];
  const float* W1x = (const float*)d_in[14];
  const float* b1x = (const float*)d_in[15];
  const float* W2x = (const float*)d_in[16];
  const float* W1y = (const float*)d_in[17];
  const float* b1y = (const float*)d_in[18];
  const float* W2y = (const float*)d_in[19];

  char* wsb = (char*)d_ws;
  f16*   Qf  = (f16*)(wsb);                 // 1216*256 f16   = 622592 B
  f16*   Kf  = (f16*)(wsb + 622592);        // 4*8*4096*32 f16= 8388608 B (head-major)
  f16*   Vtf = (f16*)(wsb + 9011200);       // 4*8*4096*32 f16= 8388608 B (head-major)
  float* rpx = (float*)(wsb + 17399808);    // 4*300*512 f32  = 2457600 B (head-major)
  float* rpy = (float*)(wsb + 19857408);    // 2457600 B
  f16*   X   = (f16*)(wsb + 22315008);      // 4*8*300*32 f16 = 614400 B (head-major)
  f16*   WT  = (f16*)(wsb + 22937600);      // 4*256*256 f16  = 524288 B

  const float scale = 0.17677669529663687f;  // 32^-0.5

  hipLaunchKernelGGL(prep_wt, dim3(4, 4, 4), dim3(256), 0, stream,
                     Wq, Wk, Wv, Wp, WT, scale);
  hipLaunchKernelGGL(rpe_kernel, dim3(B_ * NQ_, 2), dim3(256), 0, stream,
                     refpts, W1x, b1x, W2x, W1y, b1y, W2y, rpx, rpy);
  hipLaunchKernelGGL(proj_qkv, dim3(768), dim3(256), 0, stream,
                     query, kin, vin, WT, bq, bk, bv, Qf, Kf, Vtf, scale);
  hipLaunchKernelGGL(attn_mfma, dim3(B_ * H_ * 20), dim3(512), 0, stream,
                     Qf, Kf, Vtf, rpx, rpy, mask, X);
  hipLaunchKernelGGL(gemm_out, dim3(4, 19), dim3(256), 0, stream,
                     X, WT, bp, (float*)d_out);
}

// Round 19
// 216.988 us; speedup vs baseline: 1.0053x; 1.0053x over previous
//
#include <hip/hip_runtime.h>
#include <math.h>

#define B_   4
#define NQ_  300
#define DIM_ 256
#define H_   8
#define HD_  32
#define N_   4096

typedef _Float16 f16;
typedef f16   f16x8 __attribute__((ext_vector_type(8)));
typedef f16   f16x4 __attribute__((ext_vector_type(4)));
typedef float f32x4 __attribute__((ext_vector_type(4)));

// ---------------------------------------------------------------------------
// Weight prep: WT[z][n][k] = W_z[k][n] * (z==0 ? qscale : 1), f16.
// ---------------------------------------------------------------------------
__global__ __launch_bounds__(256) void prep_wt(
    const float* __restrict__ Wq, const float* __restrict__ Wk,
    const float* __restrict__ Wv, const float* __restrict__ Wp,
    f16* __restrict__ WT, float qscale)
{
  __shared__ float t[64][65];
  const int z = blockIdx.z;
  const float* W = z == 0 ? Wq : z == 1 ? Wk : z == 2 ? Wv : Wp;
  const float s = z == 0 ? qscale : 1.0f;
  f16* O = WT + (size_t)z * 65536;
  const int k0 = blockIdx.y * 64, n0 = blockIdx.x * 64;
  const int r = threadIdx.x >> 2, c0 = (threadIdx.x & 3) * 16;
#pragma unroll
  for (int c = 0; c < 16; c += 4) {
    float4 v = *(const float4*)(W + (size_t)(k0 + r) * 256 + n0 + c0 + c);
    t[r][c0 + c] = v.x; t[r][c0 + c + 1] = v.y;
    t[r][c0 + c + 2] = v.z; t[r][c0 + c + 3] = v.w;
  }
  __syncthreads();
  f16* orow = O + (size_t)(n0 + r) * 256 + k0 + c0;
#pragma unroll
  for (int c = 0; c < 16; c += 4) {
    f16x4 p;
    p[0] = (f16)(t[c0 + c + 0][r] * s);
    p[1] = (f16)(t[c0 + c + 1][r] * s);
    p[2] = (f16)(t[c0 + c + 2][r] * s);
    p[3] = (f16)(t[c0 + c + 3][r] * s);
    *(f16x4*)(orow + c) = p;
  }
}

// ---------------------------------------------------------------------------
// MFMA GEMM body: C = A @ (WT^T) + bias*scale.  WT is [n][k] f16.
// nbt = number of 64-col B tiles per block (bn-fusion: A staged once, reused).
// mode 0: fp32 row-major out; 1: f16 row-major;
// mode 3: f16 head-major  [b][h=n>>5][nrow=m&4095][d=n&31]  (K and V).
// a_f16 == 2: A is head-major X  [b][h=k>>5][q][d=k&31]  (gemm_out path).
// ---------------------------------------------------------------------------
__device__ __forceinline__ void gemm_body(
    const void* __restrict__ Ain, const f16* __restrict__ WT,
    const float* __restrict__ bias, void* __restrict__ C,
    int M, float scale, int a_f16, int mode, int bm, int bn, int nbt, int tid)
{
  __shared__ f16 As[64][40];
  __shared__ f16 Bs[4][64][40];
  const int lane = tid & 63;
  const int wv = tid >> 6;
  const int l15 = lane & 15, g = lane >> 4;
  const int arow = tid >> 2, akq = (tid & 3) * 8;

  f32x4 acc[4][4];
#pragma unroll
  for (int t = 0; t < 4; ++t)
#pragma unroll
    for (int nt = 0; nt < 4; ++nt) acc[t][nt] = (f32x4){0.f, 0.f, 0.f, 0.f};

  for (int k0 = 0; k0 < 256; k0 += 32) {
    {
      const int gm = bm + arow;
      f16x8 av;
      if (gm < M) {
        if (a_f16 == 2) {
          // head-major X: [b][h][q][32]
          const int bb2 = gm / NQ_, qq2 = gm % NQ_;
          const int kk = k0 + akq;
          av = *(const f16x8*)((const f16*)Ain +
              (((size_t)(bb2 * H_ + (kk >> 5)) * NQ_) + qq2) * 32 + (kk & 31));
        } else if (a_f16 == 1) {
          av = *(const f16x8*)((const f16*)Ain + (size_t)gm * 256 + k0 + akq);
        } else {
          const float* ap = (const float*)Ain + (size_t)gm * 256 + k0 + akq;
          float4 a0 = *(const float4*)ap;
          float4 a1 = *(const float4*)(ap + 4);
          av[0] = (f16)a0.x; av[1] = (f16)a0.y; av[2] = (f16)a0.z; av[3] = (f16)a0.w;
          av[4] = (f16)a1.x; av[5] = (f16)a1.y; av[6] = (f16)a1.z; av[7] = (f16)a1.w;
        }
      } else {
#pragma unroll
        for (int i = 0; i < 8; ++i) av[i] = (f16)0.f;
      }
      *(f16x8*)&As[arow][akq] = av;
      for (int t = 0; t < nbt; ++t)
        *(f16x8*)&Bs[t][arow][akq] =
            *(const f16x8*)(WT + (size_t)(bn + t * 64 + arow) * 256 + k0 + akq);
    }
    __syncthreads();
    const f16x8 af = *(const f16x8*)&As[wv * 16 + l15][g * 8];
    for (int t = 0; t < nbt; ++t) {
#pragma unroll
      for (int nt = 0; nt < 4; ++nt) {
        const f16x8 bf = *(const f16x8*)&Bs[t][nt * 16 + l15][g * 8];
        acc[t][nt] = __builtin_amdgcn_mfma_f32_16x16x32_f16(af, bf, acc[t][nt], 0, 0, 0);
      }
    }
    __syncthreads();
  }

  for (int t = 0; t < nbt; ++t) {
#pragma unroll
    for (int nt = 0; nt < 4; ++nt) {
      const int n = bn + t * 64 + nt * 16 + l15;
      const float bv = bias[n] * scale;
#pragma unroll
      for (int r = 0; r < 4; ++r) {
        const int m = bm + wv * 16 + g * 4 + r;
        if (m >= M) continue;
        const float v = acc[t][nt][r] + bv;
        if (mode == 0)      ((float*)C)[(size_t)m * 256 + n] = v;
        else if (mode == 1) ((f16*)C)[(size_t)m * 256 + n] = (f16)v;
        else                ((f16*)C)[((((size_t)(m >> 12)) * H_ + (n >> 5)) * N_
                                       + (m & 4095)) * 32 + (n & 31)] = (f16)v;
      }
    }
  }
}

// One block = 64 rows x full 256 cols (nbt=4: A staged once, 4x fewer A reads).
// Grid 768 = 8 XCDs x 96, chunked.  z=0: Q, z=1: K (head-major), z=2: V
// (head-major [b][h][n][32] -- attn stages V through LDS).
__global__ __launch_bounds__(256) void proj_qkv(
    const float* __restrict__ query, const float* __restrict__ kin,
    const float* __restrict__ vin, const f16* __restrict__ WT,
    const float* __restrict__ bq, const float* __restrict__ bk,
    const float* __restrict__ bv, f16* __restrict__ Qf,
    f16* __restrict__ Kf, f16* __restrict__ Vtf, float qscale)
{
  const int bid = blockIdx.x;
  const int lg  = (bid & 7) * 96 + (bid >> 3);   // 768 = 8 * 96, bijective
  const int z   = lg >> 8;                        // lg / 256
  const int bm  = (lg & 255) * 64;
  if (z == 0) {
    if (bm >= B_ * NQ_) return;
    gemm_body(query, WT, bq, Qf, B_ * NQ_, qscale, 0, 1, bm, 0, 4, threadIdx.x);
  } else if (z == 1) {
    gemm_body(kin, WT + 65536, bk, Kf, B_ * N_, 1.0f, 0, 3, bm, 0, 4, threadIdx.x);
  } else {
    gemm_body(vin, WT + 2 * 65536, bv, Vtf, B_ * N_, 1.0f, 0, 3, bm, 0, 4, threadIdx.x);
  }
}

__global__ __launch_bounds__(256) void gemm_out(
    const f16* __restrict__ X, const f16* __restrict__ WT,
    const float* __restrict__ bp, float* __restrict__ out)
{
  gemm_body(X, WT + 3 * 65536, bp, out, B_ * NQ_, 1.0f, 2, 0,
            blockIdx.y * 64, blockIdx.x * 64, 1, threadIdx.x);
}

// ---------------------------------------------------------------------------
// RPE MLP, fp32 (rpe ~±1500; must not round). lane = position j, wave owns a
// 128-wide r-slice; all weight reads wave-uniform -> scalar loads, no LDS.
// Output layout head-major: out[q][h*64 + j] so attn reads dense 256B runs.
// ---------------------------------------------------------------------------
__global__ __launch_bounds__(256) void rpe_kernel(
    const float* __restrict__ refpts,
    const float* __restrict__ W1x, const float* __restrict__ b1x, const float* __restrict__ W2x,
    const float* __restrict__ W1y, const float* __restrict__ b1y, const float* __restrict__ W2y,
    float* __restrict__ rpx, float* __restrict__ rpy)
{
  __shared__ float sRed[4][64][9];   // pad 9: head-major read is stride-9, conflict-free
  const int tid = threadIdx.x;
  const int lane = tid & 63;
  const int wv = __builtin_amdgcn_readfirstlane(tid >> 6);
  const int bq = blockIdx.x;
  const int axis = blockIdx.y;
  const float* W1 = axis ? W1y : W1x;
  const float* b1 = axis ? b1y : b1x;
  const float* W2 = axis ? W2y : W2x;
  float* out = axis ? rpy : rpx;

  const float c  = refpts[bq * 4 + axis];
  const float sz = refpts[bq * 4 + 2 + axis];
  const float pos = (lane + 0.5f) * 16.0f;
  const float d0 = c - 0.5f * sz - pos;
  const float d1 = c + 0.5f * sz - pos;
  float acc[8] = {};
  const int r0 = wv * 128;
#pragma unroll 4
  for (int i = 0; i < 128; ++i) {
    const int r = r0 + i;
    const float w10 = W1[r], w11 = W1[512 + r], bb = b1[r];
    const float hv = fmaxf(fmaf(d0, w10, fmaf(d1, w11, bb)), 0.0f);
    const float* w2r = W2 + r * 8;
#pragma unroll
    for (int hh = 0; hh < 8; ++hh) acc[hh] += hv * w2r[hh];
  }
#pragma unroll
  for (int hh = 0; hh < 8; ++hh) sRed[wv][lane][hh] = acc[hh];
  __syncthreads();
  for (int idx = tid; idx < 512; idx += 256) {
    const int hh = idx >> 6, jj = idx & 63;       // out[q][hh*64 + jj]
    out[(size_t)bq * 512 + idx] =
        sRed[0][jj][hh] + sRed[1][jj][hh] + sRed[2][jj][hh] + sRed[3][jj][hh];
  }
}

// ---------------------------------------------------------------------------
// MFMA attention, 2-deep software-pipelined K/V loads.
// R17 post-mortem: at __launch_bounds__(512,4) the 128-VGPR cap was below the
// pipeline's peak pressure -> allocator shrank to 64 VGPR and SPILLED the
// buffer arrays to scratch (WRITE_SIZE 0.6->40MB, FETCH +19MB, attn 50us,
// total regressed 203->218).  Fix: (512,2) -> 256-VGPR budget.  LDS is 62KB
// -> 2 blocks/CU max anyway; if VGPR lands <=128 we keep 2 blocks + pipeline,
// if 129-256 we run 1 block/CU with ILP covering latency (the pipeline's
// purpose).  Kill rule: WRITE_SIZE still >5MB -> revert to R13 attn.
// ---------------------------------------------------------------------------
__global__ __launch_bounds__(512, 2) void attn_mfma(
    const f16* __restrict__ Qf, const f16* __restrict__ Kf,
    const f16* __restrict__ Vtf, const float* __restrict__ rpx,
    const float* __restrict__ rpy, const int* __restrict__ mask,
    f16* __restrict__ X)
{
  __shared__ float smask[N_];          // -100*log2e*mask
  __shared__ float srx[16][68];        // rpe_x * log2e
  __shared__ float sry[16][68];        // rpe_y * log2e
  __shared__ union {
    f16 vtile[8][64 * 36];             // per-wave V tile, 72B row stride
    struct {
      float mO[7][8][64];
      float mlm[7][16];
      float mll[7][16];
    } m;
  } ovl;

  const int tid = threadIdx.x;
  const int lane = tid & 63;
  const int kh = tid >> 6;
  // XCD-aware swizzle: grid is 640 = 8 XCDs * 80; HW assigns XCD = bid % 8.
  const int bid = blockIdx.x;
  const int lg  = (bid & 7) * 80 + (bid >> 3);
  const int qg = lg % 20;
  const int h  = (lg / 20) % H_;
  const int b  = lg / (20 * H_);
  const int q0 = qg * 16;
  const float L2E = 1.44269504f;

  {
    const int4* mm4 = (const int4*)(mask + b * N_);
    for (int i = tid; i < N_ / 4; i += 512) {
      int4 mm = mm4[i];
      smask[4 * i + 0] = -100.f * L2E * (float)mm.x;
      smask[4 * i + 1] = -100.f * L2E * (float)mm.y;
      smask[4 * i + 2] = -100.f * L2E * (float)mm.z;
      smask[4 * i + 3] = -100.f * L2E * (float)mm.w;
    }
  }
  for (int i = tid; i < 1024; i += 512) {
    int qq = i >> 6, j = i & 63;
    int qg2 = q0 + qq; if (qg2 > NQ_ - 1) qg2 = NQ_ - 1;
    size_t base = (size_t)(b * NQ_ + qg2) * 512 + (size_t)h * 64 + j;  // head-major
    srx[qq][j] = rpx[base] * L2E;
    sry[qq][j] = rpy[base] * L2E;
  }
  __syncthreads();

  const int l15 = lane & 15, g = lane >> 4;
  const int qrow0 = q0 + l15;
  const int qa = qrow0 > NQ_ - 1 ? NQ_ - 1 : qrow0;

  const f16x8 qf0 = *(const f16x8*)(Qf + (size_t)(b * NQ_ + qa) * 256 + h * 32 + g * 8);

  f32x4 O00 = {0.f,0.f,0.f,0.f}, O01 = {0.f,0.f,0.f,0.f};
  float lacc0 = 0.f;
  float mrun0 = -1e30f;
  const f16* kb  = Kf  + (size_t)(b * H_ + h) * N_ * 32 + g * 8;  // head-major K
  const f16* vbp = Vtf + (size_t)(b * H_ + h) * N_ * 32;          // head-major V
  f16* vt = &ovl.vtile[kh][0];

  f16x8 kfA[4], vvA[4], kfB[4], vvB[4];

#define LOADKV(KF, VV, SP) do {                                                \
    const int kbase_ = kh * 512 + (SP) * 64;                                   \
    _Pragma("unroll")                                                          \
    for (int cc = 0; cc < 4; ++cc)                                             \
      KF[cc] = *(const f16x8*)(kb + (size_t)(kbase_ + cc * 16 + l15) * 32);    \
    const f16* vsrc_ = vbp + (size_t)kbase_ * 32;                              \
    _Pragma("unroll")                                                          \
    for (int c = 0; c < 4; ++c)                                                \
      VV[c] = *(const f16x8*)(vsrc_ + c * 512 + lane * 8);                     \
  } while (0)

#define COMPUTESP(KF, VV, SP) do {                                             \
    const int kbase_ = kh * 512 + (SP) * 64;                                   \
    f32x4 s0[4];                                                               \
    float lm0 = -1e30f;                                                        \
    _Pragma("unroll")                                                          \
    for (int cc = 0; cc < 4; ++cc) {                                           \
      const int k0_ = kbase_ + cc * 16;                                        \
      f32x4 S0 = __builtin_amdgcn_mfma_f32_16x16x32_f16(                       \
          KF[cc], qf0, (f32x4){0.f,0.f,0.f,0.f}, 0, 0, 0);                     \
      const float ry0 = sry[l15][k0_ >> 6];                                    \
      const float4 rx0 = *(const float4*)&srx[l15][(k0_ & 63) + g * 4];        \
      const float4 sm = *(const float4*)&smask[k0_ + g * 4];                   \
      s0[cc][0] = fmaf(S0[0], L2E, rx0.x + sm.x + ry0);                        \
      s0[cc][1] = fmaf(S0[1], L2E, rx0.y + sm.y + ry0);                        \
      s0[cc][2] = fmaf(S0[2], L2E, rx0.z + sm.z + ry0);                        \
      s0[cc][3] = fmaf(S0[3], L2E, rx0.w + sm.w + ry0);                        \
      lm0 = fmaxf(lm0, fmaxf(fmaxf(s0[cc][0], s0[cc][1]),                      \
                             fmaxf(s0[cc][2], s0[cc][3])));                    \
    }                                                                          \
    _Pragma("unroll")                                                          \
    for (int c = 0; c < 4; ++c) {                                              \
      const int row_ = c * 16 + (lane >> 2), d0_ = (lane & 3) * 8;             \
      f16x4 lo_, hi_;                                                          \
      _Pragma("unroll")                                                        \
      for (int i = 0; i < 4; ++i) { lo_[i] = VV[c][i]; hi_[i] = VV[c][4 + i]; }\
      *(f16x4*)&vt[row_ * 36 + d0_]     = lo_;                                 \
      *(f16x4*)&vt[row_ * 36 + d0_ + 4] = hi_;                                 \
    }                                                                          \
    lm0 = fmaxf(lm0, __shfl_xor(lm0, 16));                                     \
    lm0 = fmaxf(lm0, __shfl_xor(lm0, 32));                                     \
    const float mn0 = fmaxf(mrun0, lm0);                                       \
    const float f0 = exp2f(mrun0 - mn0);                                       \
    mrun0 = mn0;                                                               \
    lacc0 *= f0;                                                               \
    _Pragma("unroll")                                                          \
    for (int r = 0; r < 4; ++r) { O00[r] *= f0; O01[r] *= f0; }                \
    _Pragma("unroll")                                                          \
    for (int cc = 0; cc < 4; ++cc) {                                           \
      f16x4 pf0;                                                               \
      _Pragma("unroll")                                                        \
      for (int r = 0; r < 4; ++r) {                                            \
        const float p0 = exp2f(s0[cc][r] - mrun0);                             \
        lacc0 += p0;                                                           \
        pf0[r] = (f16)p0;                                                      \
      }                                                                        \
      f16x4 va_, vb_;                                                          \
      _Pragma("unroll")                                                        \
      for (int i = 0; i < 4; ++i) {                                            \
        const int krow_ = cc * 16 + g * 4 + i;                                 \
        va_[i] = vt[krow_ * 36 + l15];                                         \
        vb_[i] = vt[krow_ * 36 + 16 + l15];                                    \
      }                                                                        \
      O00 = __builtin_amdgcn_mfma_f32_16x16x16f16(va_, pf0, O00, 0, 0, 0);     \
      O01 = __builtin_amdgcn_mfma_f32_16x16x16f16(vb_, pf0, O01, 0, 0, 0);     \
    }                                                                          \
  } while (0)

  // 2-deep software pipeline, fully static register-set schedule.
  LOADKV(kfA, vvA, 0);
  LOADKV(kfB, vvB, 1);
  COMPUTESP(kfA, vvA, 0);
  LOADKV(kfA, vvA, 2);
  COMPUTESP(kfB, vvB, 1);
  LOADKV(kfB, vvB, 3);
  COMPUTESP(kfA, vvA, 2);
  LOADKV(kfA, vvA, 4);
  COMPUTESP(kfB, vvB, 3);
  LOADKV(kfB, vvB, 5);
  COMPUTESP(kfA, vvA, 4);
  LOADKV(kfA, vvA, 6);
  COMPUTESP(kfB, vvB, 5);
  LOADKV(kfB, vvB, 7);
  COMPUTESP(kfA, vvA, 6);
  COMPUTESP(kfB, vvB, 7);

#undef LOADKV
#undef COMPUTESP

  lacc0 += __shfl_xor(lacc0, 16); lacc0 += __shfl_xor(lacc0, 32);

  __syncthreads();   // all waves done with vtile before mO overlays it
  if (kh > 0) {
#pragma unroll
    for (int r = 0; r < 4; ++r) {
      ovl.m.mO[kh - 1][r][lane]     = O00[r];
      ovl.m.mO[kh - 1][4 + r][lane] = O01[r];
    }
    if (lane < 16) {
      ovl.m.mlm[kh - 1][lane] = mrun0;
      ovl.m.mll[kh - 1][lane] = lacc0;
    }
  }
  __syncthreads();
  if (kh == 0) {
    float ms = mrun0;
#pragma unroll
    for (int w = 0; w < 7; ++w) ms = fmaxf(ms, ovl.m.mlm[w][l15]);
    const float fme = exp2f(mrun0 - ms);
    float lt = lacc0 * fme;
    float fw[7];
#pragma unroll
    for (int w = 0; w < 7; ++w) {
      fw[w] = exp2f(ovl.m.mlm[w][l15] - ms);
      lt += ovl.m.mll[w][l15] * fw[w];
    }
    const float rl = 1.0f / lt;
    if (qrow0 < NQ_) {
      f16* xr = X + ((size_t)(b * H_ + h) * NQ_ + qrow0) * 32;   // head-major X
      f16x4 p0, p1;
#pragma unroll
      for (int r = 0; r < 4; ++r) {
        float o0 = O00[r] * fme, o1 = O01[r] * fme;
#pragma unroll
        for (int w = 0; w < 7; ++w) {
          o0 += ovl.m.mO[w][r][lane] * fw[w];
          o1 += ovl.m.mO[w][4 + r][lane] * fw[w];
        }
        p0[r] = (f16)(o0 * rl);
        p1[r] = (f16)(o1 * rl);
      }
      *(f16x4*)(xr + g * 4) = p0;
      *(f16x4*)(xr + 16 + g * 4) = p1;
    }
  }
}

// ---------------------------------------------------------------------------
extern "C" void kernel_launch(void* const* d_in, const int* in_sizes, int n_in,
                              void* d_out, int out_size, void* d_ws, size_t ws_size,
                              hipStream_t stream)
{
  const float* query  = (const float*)d_in[0];
  const float* refpts = (const float*)d_in[1];
  const float* kin    = (const float*)d_in[2];
  const float* vin    = (const float*)d_in[3];
  const int*   mask   = (const int*)d_in[5];
  const float* Wq = (const float*)d_in[6];
  const float* bq = (const float*)d_in[7];
  const float* Wk = (const float*)d_in[8];
  const float* bk = (const float*)d_in[9];
  const float* Wv = (const float*)d_in[10];
  const float* bv = (const float*)d_in[11];
  const float* Wp = (const float*)d_in[12];
  const float* bp = (const float*)d_in[13];
  const float* W1x = (const float*)d_in[14];
  const float* b1x = (const float*)d_in[15];
  const float* W2x = (const float*)d_in[16];
  const float* W1y = (const float*)d_in[17];
  const float* b1y = (const float*)d_in[18];
  const float* W2y = (const float*)d_in[19];

  char* wsb = (char*)d_ws;
  f16*   Qf  = (f16*)(wsb);                 // 1216*256 f16   = 622592 B
  f16*   Kf  = (f16*)(wsb + 622592);        // 4*8*4096*32 f16= 8388608 B (head-major)
  f16*   Vtf = (f16*)(wsb + 9011200);       // 4*8*4096*32 f16= 8388608 B (head-major)
  float* rpx = (float*)(wsb + 17399808);    // 4*300*512 f32  = 2457600 B (head-major)
  float* rpy = (float*)(wsb + 19857408);    // 2457600 B
  f16*   X   = (f16*)(wsb + 22315008);      // 4*8*300*32 f16 = 614400 B (head-major)
  f16*   WT  = (f16*)(wsb + 22937600);      // 4*256*256 f16  = 524288 B

  const float scale = 0.17677669529663687f;  // 32^-0.5

  hipLaunchKernelGGL(prep_wt, dim3(4, 4, 4), dim3(256), 0, stream,
                     Wq, Wk, Wv, Wp, WT, scale);
  hipLaunchKernelGGL(rpe_kernel, dim3(B_ * NQ_, 2), dim3(256), 0, stream,
                     refpts, W1x, b1x, W2x, W1y, b1y, W2y, rpx, rpy);
  hipLaunchKernelGGL(proj_qkv, dim3(768), dim3(256), 0, stream,
                     query, kin, vin, WT, bq, bk, bv, Qf, Kf, Vtf, scale);
  hipLaunchKernelGGL(attn_mfma, dim3(B_ * H_ * 20), dim3(512), 0, stream,
                     Qf, Kf, Vtf, rpx, rpy, mask, X);
  hipLaunchKernelGGL(gemm_out, dim3(4, 19), dim3(256), 0, stream,
                     X, WT, bp, (float*)d_out);
}

// Round 22
// 201.819 us; speedup vs baseline: 1.0809x; 1.0752x over previous
//
#include <hip/hip_runtime.h>
#include <math.h>

#define B_   4
#define NQ_  300
#define DIM_ 256
#define H_   8
#define HD_  32
#define N_   4096

typedef _Float16 f16;
typedef f16   f16x8 __attribute__((ext_vector_type(8)));
typedef f16   f16x4 __attribute__((ext_vector_type(4)));
typedef float f32x4 __attribute__((ext_vector_type(4)));

// ---------------------------------------------------------------------------
// Weight prep: WT[z][n][k] = W_z[k][n] * (z==0 ? qscale : 1), f16.
// ---------------------------------------------------------------------------
__global__ __launch_bounds__(256) void prep_wt(
    const float* __restrict__ Wq, const float* __restrict__ Wk,
    const float* __restrict__ Wv, const float* __restrict__ Wp,
    f16* __restrict__ WT, float qscale)
{
  __shared__ float t[64][65];
  const int z = blockIdx.z;
  const float* W = z == 0 ? Wq : z == 1 ? Wk : z == 2 ? Wv : Wp;
  const float s = z == 0 ? qscale : 1.0f;
  f16* O = WT + (size_t)z * 65536;
  const int k0 = blockIdx.y * 64, n0 = blockIdx.x * 64;
  const int r = threadIdx.x >> 2, c0 = (threadIdx.x & 3) * 16;
#pragma unroll
  for (int c = 0; c < 16; c += 4) {
    float4 v = *(const float4*)(W + (size_t)(k0 + r) * 256 + n0 + c0 + c);
    t[r][c0 + c] = v.x; t[r][c0 + c + 1] = v.y;
    t[r][c0 + c + 2] = v.z; t[r][c0 + c + 3] = v.w;
  }
  __syncthreads();
  f16* orow = O + (size_t)(n0 + r) * 256 + k0 + c0;
#pragma unroll
  for (int c = 0; c < 16; c += 4) {
    f16x4 p;
    p[0] = (f16)(t[c0 + c + 0][r] * s);
    p[1] = (f16)(t[c0 + c + 1][r] * s);
    p[2] = (f16)(t[c0 + c + 2][r] * s);
    p[3] = (f16)(t[c0 + c + 3][r] * s);
    *(f16x4*)(orow + c) = p;
  }
}

// ---------------------------------------------------------------------------
// MFMA GEMM body: C = A @ (WT^T) + bias*scale.  WT is [n][k] f16.
// nbt = number of 64-col B tiles per block (bn-fusion: A staged once, reused).
// mode 0: fp32 row-major out; 1: f16 row-major;
// mode 3: f16 head-major  [b][h=n>>5][nrow=m&4095][d=n&31]  (K and V).
// a_f16 == 2: A is head-major X  [b][h=k>>5][q][d=k&31]  (gemm_out path).
// ---------------------------------------------------------------------------
__device__ __forceinline__ void gemm_body(
    const void* __restrict__ Ain, const f16* __restrict__ WT,
    const float* __restrict__ bias, void* __restrict__ C,
    int M, float scale, int a_f16, int mode, int bm, int bn, int nbt, int tid)
{
  __shared__ f16 As[64][40];
  __shared__ f16 Bs[4][64][40];
  const int lane = tid & 63;
  const int wv = tid >> 6;
  const int l15 = lane & 15, g = lane >> 4;
  const int arow = tid >> 2, akq = (tid & 3) * 8;

  f32x4 acc[4][4];
#pragma unroll
  for (int t = 0; t < 4; ++t)
#pragma unroll
    for (int nt = 0; nt < 4; ++nt) acc[t][nt] = (f32x4){0.f, 0.f, 0.f, 0.f};

  for (int k0 = 0; k0 < 256; k0 += 32) {
    {
      const int gm = bm + arow;
      f16x8 av;
      if (gm < M) {
        if (a_f16 == 2) {
          // head-major X: [b][h][q][32]
          const int bb2 = gm / NQ_, qq2 = gm % NQ_;
          const int kk = k0 + akq;
          av = *(const f16x8*)((const f16*)Ain +
              (((size_t)(bb2 * H_ + (kk >> 5)) * NQ_) + qq2) * 32 + (kk & 31));
        } else if (a_f16 == 1) {
          av = *(const f16x8*)((const f16*)Ain + (size_t)gm * 256 + k0 + akq);
        } else {
          const float* ap = (const float*)Ain + (size_t)gm * 256 + k0 + akq;
          float4 a0 = *(const float4*)ap;
          float4 a1 = *(const float4*)(ap + 4);
          av[0] = (f16)a0.x; av[1] = (f16)a0.y; av[2] = (f16)a0.z; av[3] = (f16)a0.w;
          av[4] = (f16)a1.x; av[5] = (f16)a1.y; av[6] = (f16)a1.z; av[7] = (f16)a1.w;
        }
      } else {
#pragma unroll
        for (int i = 0; i < 8; ++i) av[i] = (f16)0.f;
      }
      *(f16x8*)&As[arow][akq] = av;
      for (int t = 0; t < nbt; ++t)
        *(f16x8*)&Bs[t][arow][akq] =
            *(const f16x8*)(WT + (size_t)(bn + t * 64 + arow) * 256 + k0 + akq);
    }
    __syncthreads();
    const f16x8 af = *(const f16x8*)&As[wv * 16 + l15][g * 8];
    for (int t = 0; t < nbt; ++t) {
#pragma unroll
      for (int nt = 0; nt < 4; ++nt) {
        const f16x8 bf = *(const f16x8*)&Bs[t][nt * 16 + l15][g * 8];
        acc[t][nt] = __builtin_amdgcn_mfma_f32_16x16x32_f16(af, bf, acc[t][nt], 0, 0, 0);
      }
    }
    __syncthreads();
  }

  for (int t = 0; t < nbt; ++t) {
#pragma unroll
    for (int nt = 0; nt < 4; ++nt) {
      const int n = bn + t * 64 + nt * 16 + l15;
      const float bv = bias[n] * scale;
#pragma unroll
      for (int r = 0; r < 4; ++r) {
        const int m = bm + wv * 16 + g * 4 + r;
        if (m >= M) continue;
        const float v = acc[t][nt][r] + bv;
        if (mode == 0)      ((float*)C)[(size_t)m * 256 + n] = v;
        else if (mode == 1) ((f16*)C)[(size_t)m * 256 + n] = (f16)v;
        else                ((f16*)C)[((((size_t)(m >> 12)) * H_ + (n >> 5)) * N_
                                       + (m & 4095)) * 32 + (n & 31)] = (f16)v;
      }
    }
  }
}

// One block = 64 rows x full 256 cols (nbt=4: A staged once, 4x fewer A reads).
// Grid 768 = 8 XCDs x 96, chunked.  z=0: Q, z=1: K (head-major), z=2: V
// (head-major [b][h][n][32] -- attn stages V through LDS).
__global__ __launch_bounds__(256) void proj_qkv(
    const float* __restrict__ query, const float* __restrict__ kin,
    const float* __restrict__ vin, const f16* __restrict__ WT,
    const float* __restrict__ bq, const float* __restrict__ bk,
    const float* __restrict__ bv, f16* __restrict__ Qf,
    f16* __restrict__ Kf, f16* __restrict__ Vtf, float qscale)
{
  const int bid = blockIdx.x;
  const int lg  = (bid & 7) * 96 + (bid >> 3);   // 768 = 8 * 96, bijective
  const int z   = lg >> 8;                        // lg / 256
  const int bm  = (lg & 255) * 64;
  if (z == 0) {
    if (bm >= B_ * NQ_) return;
    gemm_body(query, WT, bq, Qf, B_ * NQ_, qscale, 0, 1, bm, 0, 4, threadIdx.x);
  } else if (z == 1) {
    gemm_body(kin, WT + 65536, bk, Kf, B_ * N_, 1.0f, 0, 3, bm, 0, 4, threadIdx.x);
  } else {
    gemm_body(vin, WT + 2 * 65536, bv, Vtf, B_ * N_, 1.0f, 0, 3, bm, 0, 4, threadIdx.x);
  }
}

__global__ __launch_bounds__(256) void gemm_out(
    const f16* __restrict__ X, const f16* __restrict__ WT,
    const float* __restrict__ bp, float* __restrict__ out)
{
  gemm_body(X, WT + 3 * 65536, bp, out, B_ * NQ_, 1.0f, 2, 0,
            blockIdx.y * 64, blockIdx.x * 64, 1, threadIdx.x);
}

// ---------------------------------------------------------------------------
// RPE MLP, fp32 (rpe ~±1500; must not round). lane = position j, wave owns a
// 128-wide r-slice; all weight reads wave-uniform -> scalar loads, no LDS.
// Output layout head-major: out[q][h*64 + j] so attn reads dense 256B runs.
// ---------------------------------------------------------------------------
__global__ __launch_bounds__(256) void rpe_kernel(
    const float* __restrict__ refpts,
    const float* __restrict__ W1x, const float* __restrict__ b1x, const float* __restrict__ W2x,
    const float* __restrict__ W1y, const float* __restrict__ b1y, const float* __restrict__ W2y,
    float* __restrict__ rpx, float* __restrict__ rpy)
{
  __shared__ float sRed[4][64][9];   // pad 9: head-major read is stride-9, conflict-free
  const int tid = threadIdx.x;
  const int lane = tid & 63;
  const int wv = __builtin_amdgcn_readfirstlane(tid >> 6);
  const int bq = blockIdx.x;
  const int axis = blockIdx.y;
  const float* W1 = axis ? W1y : W1x;
  const float* b1 = axis ? b1y : b1x;
  const float* W2 = axis ? W2y : W2x;
  float* out = axis ? rpy : rpx;

  const float c  = refpts[bq * 4 + axis];
  const float sz = refpts[bq * 4 + 2 + axis];
  const float pos = (lane + 0.5f) * 16.0f;
  const float d0 = c - 0.5f * sz - pos;
  const float d1 = c + 0.5f * sz - pos;
  float acc[8] = {};
  const int r0 = wv * 128;
#pragma unroll 4
  for (int i = 0; i < 128; ++i) {
    const int r = r0 + i;
    const float w10 = W1[r], w11 = W1[512 + r], bb = b1[r];
    const float hv = fmaxf(fmaf(d0, w10, fmaf(d1, w11, bb)), 0.0f);
    const float* w2r = W2 + r * 8;
#pragma unroll
    for (int hh = 0; hh < 8; ++hh) acc[hh] += hv * w2r[hh];
  }
#pragma unroll
  for (int hh = 0; hh < 8; ++hh) sRed[wv][lane][hh] = acc[hh];
  __syncthreads();
  for (int idx = tid; idx < 512; idx += 256) {
    const int hh = idx >> 6, jj = idx & 63;       // out[q][hh*64 + jj]
    out[(size_t)bq * 512 + idx] =
        sRed[0][jj][hh] + sRed[1][jj][hh] + sRed[2][jj][hh] + sRed[3][jj][hh];
  }
}

// ---------------------------------------------------------------------------
// MFMA attention — EXACT R13 design (verified 203.3us total), reverted after
// the pipeline arc concluded: R17 (512,4)+pipe spilled (WRITE 40MB, 218us);
// R19 (512,2)+pipe fixed the spill but halved occupancy and tripled LDS
// conflicts (attn 48.2us vs ~35us here, total 217us).  Matches guide m99/m100:
// implicit wave-level overlap (2 blocks/CU TLP) already covers per-sp latency;
// explicit source pipelining is net-negative on this structure.
// Block = (b,h,16q), 8 waves x 512 keys; V head-major staged via wave-private
// LDS tile (R13's request-queue fix: 1 segment/load vs 16); exact online
// softmax in log2 domain; 8 partials merged via LDS overlay.
// ---------------------------------------------------------------------------
__global__ __launch_bounds__(512, 4) void attn_mfma(
    const f16* __restrict__ Qf, const f16* __restrict__ Kf,
    const f16* __restrict__ Vtf, const float* __restrict__ rpx,
    const float* __restrict__ rpy, const int* __restrict__ mask,
    f16* __restrict__ X)
{
  __shared__ float smask[N_];          // -100*log2e*mask
  __shared__ float srx[16][68];        // rpe_x * log2e
  __shared__ float sry[16][68];        // rpe_y * log2e
  __shared__ union {
    f16 vtile[8][64 * 36];             // per-wave V tile, 72B row stride
    struct {
      float mO[7][8][64];
      float mlm[7][16];
      float mll[7][16];
    } m;
  } ovl;

  const int tid = threadIdx.x;
  const int lane = tid & 63;
  const int kh = tid >> 6;
  // XCD-aware swizzle: grid is 640 = 8 XCDs * 80; HW assigns XCD = bid % 8.
  const int bid = blockIdx.x;
  const int lg  = (bid & 7) * 80 + (bid >> 3);
  const int qg = lg % 20;
  const int h  = (lg / 20) % H_;
  const int b  = lg / (20 * H_);
  const int q0 = qg * 16;
  const float L2E = 1.44269504f;

  {
    const int4* mm4 = (const int4*)(mask + b * N_);
    for (int i = tid; i < N_ / 4; i += 512) {
      int4 mm = mm4[i];
      smask[4 * i + 0] = -100.f * L2E * (float)mm.x;
      smask[4 * i + 1] = -100.f * L2E * (float)mm.y;
      smask[4 * i + 2] = -100.f * L2E * (float)mm.z;
      smask[4 * i + 3] = -100.f * L2E * (float)mm.w;
    }
  }
  for (int i = tid; i < 1024; i += 512) {
    int qq = i >> 6, j = i & 63;
    int qg2 = q0 + qq; if (qg2 > NQ_ - 1) qg2 = NQ_ - 1;
    size_t base = (size_t)(b * NQ_ + qg2) * 512 + (size_t)h * 64 + j;  // head-major
    srx[qq][j] = rpx[base] * L2E;
    sry[qq][j] = rpy[base] * L2E;
  }
  __syncthreads();

  const int l15 = lane & 15, g = lane >> 4;
  const int qrow0 = q0 + l15;
  const int qa = qrow0 > NQ_ - 1 ? NQ_ - 1 : qrow0;

  const f16x8 qf0 = *(const f16x8*)(Qf + (size_t)(b * NQ_ + qa) * 256 + h * 32 + g * 8);

  f32x4 O00 = {0.f,0.f,0.f,0.f}, O01 = {0.f,0.f,0.f,0.f};
  float lacc0 = 0.f;
  float mrun0 = -1e30f;
  const f16* kb = Kf  + (size_t)(b * H_ + h) * N_ * 32 + g * 8;  // head-major K
  const f16* vb = Vtf + (size_t)(b * H_ + h) * N_ * 32;          // head-major V
  f16* vt = &ovl.vtile[kh][0];

  for (int sp = 0; sp < 8; ++sp) {
    const int kbase = kh * 512 + sp * 64;
    // ---- issue K loads (coalesced 1KB each), then V-stage loads (4x1KB) ----
    f16x8 kf[4];
#pragma unroll
    for (int cc = 0; cc < 4; ++cc)
      kf[cc] = *(const f16x8*)(kb + (size_t)(kbase + cc * 16 + l15) * 32);
    const f16* vsrc = vb + (size_t)kbase * 32;   // contiguous 4KB (64 rows x 64B)
    f16x8 vv[4];
#pragma unroll
    for (int c = 0; c < 4; ++c)
      vv[c] = *(const f16x8*)(vsrc + c * 512 + lane * 8);
    // ---- pass A: QK + fixup (waits only on kf; vv stays in flight) ----
    f32x4 s0[4];
    float lm0 = -1e30f;
#pragma unroll
    for (int cc = 0; cc < 4; ++cc) {
      const int k0 = kbase + cc * 16;
      f32x4 S0 = __builtin_amdgcn_mfma_f32_16x16x32_f16(
          kf[cc], qf0, (f32x4){0.f,0.f,0.f,0.f}, 0, 0, 0);
      const float ry0 = sry[l15][k0 >> 6];
      const float4 rx0 = *(const float4*)&srx[l15][(k0 & 63) + g * 4];
      const float4 sm = *(const float4*)&smask[k0 + g * 4];
      s0[cc][0] = fmaf(S0[0], L2E, rx0.x + sm.x + ry0);
      s0[cc][1] = fmaf(S0[1], L2E, rx0.y + sm.y + ry0);
      s0[cc][2] = fmaf(S0[2], L2E, rx0.z + sm.z + ry0);
      s0[cc][3] = fmaf(S0[3], L2E, rx0.w + sm.w + ry0);
      lm0 = fmaxf(lm0, fmaxf(fmaxf(s0[cc][0], s0[cc][1]), fmaxf(s0[cc][2], s0[cc][3])));
    }
    // ---- write V tile to wave-private LDS (2x b64 per chunk; 72B rows) ----
#pragma unroll
    for (int c = 0; c < 4; ++c) {
      const int row = c * 16 + (lane >> 2), d0 = (lane & 3) * 8;
      f16x4 lo, hi;
#pragma unroll
      for (int i = 0; i < 4; ++i) { lo[i] = vv[c][i]; hi[i] = vv[c][4 + i]; }
      *(f16x4*)&vt[row * 36 + d0]     = lo;
      *(f16x4*)&vt[row * 36 + d0 + 4] = hi;
    }
    lm0 = fmaxf(lm0, __shfl_xor(lm0, 16));
    lm0 = fmaxf(lm0, __shfl_xor(lm0, 32));
    const float mn0 = fmaxf(mrun0, lm0);
    const float f0 = exp2f(mrun0 - mn0);
    mrun0 = mn0;
    lacc0 *= f0;
#pragma unroll
    for (int r = 0; r < 4; ++r) { O00[r] *= f0; O01[r] *= f0; }
    // ---- pass B: exp2 + PV (V^T fragments from LDS, conflict-free u16) ----
#pragma unroll
    for (int cc = 0; cc < 4; ++cc) {
      f16x4 pf0;
#pragma unroll
      for (int r = 0; r < 4; ++r) {
        const float p0 = exp2f(s0[cc][r] - mrun0);
        lacc0 += p0;
        pf0[r] = (f16)p0;
      }
      f16x4 va_, vb_;
#pragma unroll
      for (int i = 0; i < 4; ++i) {
        const int krow = cc * 16 + g * 4 + i;
        va_[i] = vt[krow * 36 + l15];
        vb_[i] = vt[krow * 36 + 16 + l15];
      }
      O00 = __builtin_amdgcn_mfma_f32_16x16x16f16(va_, pf0, O00, 0, 0, 0);
      O01 = __builtin_amdgcn_mfma_f32_16x16x16f16(vb_, pf0, O01, 0, 0, 0);
    }
  }

  lacc0 += __shfl_xor(lacc0, 16); lacc0 += __shfl_xor(lacc0, 32);

  __syncthreads();   // all waves done with vtile before mO overlays it
  if (kh > 0) {
#pragma unroll
    for (int r = 0; r < 4; ++r) {
      ovl.m.mO[kh - 1][r][lane]     = O00[r];
      ovl.m.mO[kh - 1][4 + r][lane] = O01[r];
    }
    if (lane < 16) {
      ovl.m.mlm[kh - 1][lane] = mrun0;
      ovl.m.mll[kh - 1][lane] = lacc0;
    }
  }
  __syncthreads();
  if (kh == 0) {
    float ms = mrun0;
#pragma unroll
    for (int w = 0; w < 7; ++w) ms = fmaxf(ms, ovl.m.mlm[w][l15]);
    const float fme = exp2f(mrun0 - ms);
    float lt = lacc0 * fme;
    float fw[7];
#pragma unroll
    for (int w = 0; w < 7; ++w) {
      fw[w] = exp2f(ovl.m.mlm[w][l15] - ms);
      lt += ovl.m.mll[w][l15] * fw[w];
    }
    const float rl = 1.0f / lt;
    if (qrow0 < NQ_) {
      f16* xr = X + ((size_t)(b * H_ + h) * NQ_ + qrow0) * 32;   // head-major X
      f16x4 p0, p1;
#pragma unroll
      for (int r = 0; r < 4; ++r) {
        float o0 = O00[r] * fme, o1 = O01[r] * fme;
#pragma unroll
        for (int w = 0; w < 7; ++w) {
          o0 += ovl.m.mO[w][r][lane] * fw[w];
          o1 += ovl.m.mO[w][4 + r][lane] * fw[w];
        }
        p0[r] = (f16)(o0 * rl);
        p1[r] = (f16)(o1 * rl);
      }
      *(f16x4*)(xr + g * 4) = p0;
      *(f16x4*)(xr + 16 + g * 4) = p1;
    }
  }
}

// ---------------------------------------------------------------------------
extern "C" void kernel_launch(void* const* d_in, const int* in_sizes, int n_in,
                              void* d_out, int out_size, void* d_ws, size_t ws_size,
                              hipStream_t stream)
{
  const float* query  = (const float*)d_in[0];
  const float* refpts = (const float*)d_in[1];
  const float* kin    = (const float*)d_in[2];
  const float* vin    = (const float*)d_in[3];
  const int*   mask   = (const int*)d_in[5];
  const float* Wq = (const float*)d_in[6];
  const float* bq = (const float*)d_in[7];
  const float* Wk = (const float*)d_in[8];
  const float* bk = (const float*)d_in[9];
  const float* Wv = (const float*)d_in[10];
  const float* bv = (const float*)d_in[11];
  const float* Wp = (const float*)d_in[12];
  const float* bp = (const float*)d_in[13];
  const float* W1x = (const float*)d_in[14];
  const float* b1x = (const float*)d_in[15];
  const float* W2x = (const float*)d_in[16];
  const float* W1y = (const float*)d_in[17];
  const float* b1y = (const float*)d_in[18];
  const float* W2y = (const float*)d_in[19];

  char* wsb = (char*)d_ws;
  f16*   Qf  = (f16*)(wsb);                 // 1216*256 f16   = 622592 B
  f16*   Kf  = (f16*)(wsb + 622592);        // 4*8*4096*32 f16= 8388608 B (head-major)
  f16*   Vtf = (f16*)(wsb + 9011200);       // 4*8*4096*32 f16= 8388608 B (head-major)
  float* rpx = (float*)(wsb + 17399808);    // 4*300*512 f32  = 2457600 B (head-major)
  float* rpy = (float*)(wsb + 19857408);    // 2457600 B
  f16*   X   = (f16*)(wsb + 22315008);      // 4*8*300*32 f16 = 614400 B (head-major)
  f16*   WT  = (f16*)(wsb + 22937600);      // 4*256*256 f16  = 524288 B

  const float scale = 0.17677669529663687f;  // 32^-0.5

  hipLaunchKernelGGL(prep_wt, dim3(4, 4, 4), dim3(256), 0, stream,
                     Wq, Wk, Wv, Wp, WT, scale);
  hipLaunchKernelGGL(rpe_kernel, dim3(B_ * NQ_, 2), dim3(256), 0, stream,
                     refpts, W1x, b1x, W2x, W1y, b1y, W2y, rpx, rpy);
  hipLaunchKernelGGL(proj_qkv, dim3(768), dim3(256), 0, stream,
                     query, kin, vin, WT, bq, bk, bv, Qf, Kf, Vtf, scale);
  hipLaunchKernelGGL(attn_mfma, dim3(B_ * H_ * 20), dim3(512), 0, stream,
                     Qf, Kf, Vtf, rpx, rpy, mask, X);
  hipLaunchKernelGGL(gemm_out, dim3(4, 19), dim3(256), 0, stream,
                     X, WT, bp, (float*)d_out);
}